// Round 1
// baseline (574.729 us; speedup 1.0000x reference)
//
#include <hip/hip_runtime.h>

#define H 6
#define D 128

// ---------------- CSR build (per launch; deterministic input) ----------------

__global__ __launch_bounds__(256) void hist_kernel(const int* __restrict__ dst,
                                                   int* __restrict__ deg, int E) {
    int e = blockIdx.x * blockDim.x + threadIdx.x;
    if (e < E) atomicAdd(&deg[dst[e]], 1);
}

__global__ __launch_bounds__(1024) void scan_kernel(const int* __restrict__ deg,
                                                    int* __restrict__ rowptr, int n) {
    __shared__ int s[1024];
    __shared__ int carry;
    if (threadIdx.x == 0) carry = 0;
    __syncthreads();
    for (int base = 0; base < n; base += 1024) {
        int i = base + (int)threadIdx.x;
        int v = (i < n) ? deg[i] : 0;
        s[threadIdx.x] = v;
        __syncthreads();
        for (int off = 1; off < 1024; off <<= 1) {
            int t = (threadIdx.x >= (unsigned)off) ? s[threadIdx.x - off] : 0;
            __syncthreads();
            s[threadIdx.x] += t;
            __syncthreads();
        }
        if (i < n) rowptr[i] = carry + s[threadIdx.x] - v;  // exclusive prefix
        __syncthreads();
        if (threadIdx.x == 0) carry += s[1023];
        __syncthreads();
    }
}

// scatter uses rowptr as a cursor; afterwards rowptr[n] == end offset of node n.
__global__ __launch_bounds__(256) void scatter_kernel(const int* __restrict__ src,
                                                      const int* __restrict__ dst,
                                                      int* __restrict__ rowcur,
                                                      int* __restrict__ col, int E) {
    int e = blockIdx.x * blockDim.x + threadIdx.x;
    if (e < E) {
        int p = atomicAdd(&rowcur[dst[e]], 1);
        col[p] = src[e];
    }
}

// ---------------- per-layer kernels ----------------

// wa[k][j] = sum_c W[k][h*128+c] * att[h][c], j<6 -> att_src (h=j), j>=6 -> att_dst (h=j-6)
__global__ __launch_bounds__(256) void fold_att_kernel(const float* __restrict__ W,
                                                       const float* __restrict__ att_src,
                                                       const float* __restrict__ att_dst,
                                                       float* __restrict__ wa) {
    int t = blockIdx.x * blockDim.x + threadIdx.x;
    if (t >= 128 * 12) return;
    int k = t / 12, j = t % 12;
    int h = (j < 6) ? j : (j - 6);
    const float* att = (j < 6) ? att_src : att_dst;
    const float* wrow = W + (size_t)k * (H * D) + h * D;
    const float* arow = att + h * D;
    float s = 0.f;
    #pragma unroll 8
    for (int c = 0; c < D; c++) s += wrow[c] * arow[c];
    wa[k * 12 + j] = s;
}

// a[n][j] = x[n,:] @ wa[:,j]   (one wave per node)
__global__ __launch_bounds__(256) void compute_a_kernel(const float* __restrict__ x,
                                                        const float* __restrict__ wa,
                                                        float* __restrict__ a, int n_nodes) {
    __shared__ float swa[128 * 12];
    for (int i = threadIdx.x; i < 128 * 12; i += 256) swa[i] = wa[i];
    __syncthreads();
    int wid = (int)((blockIdx.x * blockDim.x + threadIdx.x) >> 6);
    int lane = threadIdx.x & 63;
    if (wid >= n_nodes) return;
    float x0 = x[(size_t)wid * D + lane];
    float x1 = x[(size_t)wid * D + 64 + lane];
    #pragma unroll
    for (int j = 0; j < 12; j++) {
        float p = x0 * swa[lane * 12 + j] + x1 * swa[(64 + lane) * 12 + j];
        #pragma unroll
        for (int off = 32; off; off >>= 1) p += __shfl_xor(p, off, 64);
        if (lane == 0) a[(size_t)wid * 12 + j] = p;
    }
}

// One wave per dst node: softmax over incoming edges (+implicit self loop),
// agg[n][h*128+c] = sum_e alpha_{e,h} * x[src_e][c]
__global__ __launch_bounds__(256) void aggregate_kernel(const float* __restrict__ x,
                                                        const float* __restrict__ a,
                                                        const int* __restrict__ rowend,
                                                        const int* __restrict__ deg_,
                                                        const int* __restrict__ col,
                                                        float* __restrict__ agg, int n_nodes) {
    int wid = (int)((blockIdx.x * blockDim.x + threadIdx.x) >> 6);
    int lane = threadIdx.x & 63;
    if (wid >= n_nodes) return;
    int n = wid;
    int deg = deg_[n];
    int start = rowend[n] - deg;

    float adst[H];
    #pragma unroll
    for (int h = 0; h < H; h++) adst[h] = a[(size_t)n * 12 + 6 + h];

    // pass 1: per-head max (self loop seeds the max; all lanes redundantly)
    float m[H];
    #pragma unroll
    for (int h = 0; h < H; h++) {
        float e = a[(size_t)n * 12 + h] + adst[h];
        m[h] = (e > 0.f) ? e : 0.2f * e;
    }
    for (int j = 0; j < deg; j++) {
        int s = col[start + j];
        #pragma unroll
        for (int h = 0; h < H; h++) {
            float e = a[(size_t)s * 12 + h] + adst[h];
            e = (e > 0.f) ? e : 0.2f * e;
            m[h] = fmaxf(m[h], e);
        }
    }

    // pass 2: accumulate exp-weighted sum + denom (all lanes see all edges;
    // weights identical across lanes, channels partitioned by lane)
    float d[H] = {0, 0, 0, 0, 0, 0};
    float acc0[H] = {0, 0, 0, 0, 0, 0};
    float acc1[H] = {0, 0, 0, 0, 0, 0};
    int c0 = lane, c1 = 64 + lane;
    for (int j = 0; j <= deg; j++) {
        int s = (j < deg) ? col[start + j] : n;
        float w[H];
        #pragma unroll
        for (int h = 0; h < H; h++) {
            float e = a[(size_t)s * 12 + h] + adst[h];
            e = (e > 0.f) ? e : 0.2f * e;
            w[h] = __expf(e - m[h]);
            d[h] += w[h];
        }
        float xv0 = x[(size_t)s * D + c0];
        float xv1 = x[(size_t)s * D + c1];
        #pragma unroll
        for (int h = 0; h < H; h++) {
            acc0[h] += w[h] * xv0;
            acc1[h] += w[h] * xv1;
        }
    }
    float* og = agg + (size_t)n * (H * D);
    #pragma unroll
    for (int h = 0; h < H; h++) {
        float inv = 1.0f / (d[h] + 1e-16f);
        og[h * D + c0] = acc0[h] * inv;
        og[h * D + c1] = acc1[h] * inv;
    }
}

// out[m][c] = relu( (1/6) * sum_{kk} agg[m][kk] * W[kk%128][ (kk/128)*128 + c ] + bias[c] )
#define BM 32
#define BK 32
__global__ __launch_bounds__(256) void gemm_out_kernel(const float* __restrict__ A,
                                                       const float* __restrict__ W,
                                                       const float* __restrict__ bias,
                                                       float* __restrict__ out, int M) {
    __shared__ float As[BK][BM + 4];   // transposed A tile: As[kk][m]
    __shared__ float Bs[BK][128];
    int m0 = blockIdx.x * BM;
    int tid = threadIdx.x;
    int tm = tid >> 5;    // 0..7
    int tn = tid & 31;    // 0..31

    float acc[4][4] = {{0}};

    for (int k0 = 0; k0 < H * D; k0 += BK) {
        // A tile: 32 rows x 32 k, one float4 per thread, store transposed
        {
            int r = tid >> 3;           // 0..31
            int cq = (tid & 7) * 4;     // 0..28
            int m = m0 + r;
            float4 v = make_float4(0, 0, 0, 0);
            if (m < M) v = *(const float4*)(A + (size_t)m * (H * D) + k0 + cq);
            As[cq + 0][r] = v.x;
            As[cq + 1][r] = v.y;
            As[cq + 2][r] = v.z;
            As[cq + 3][r] = v.w;
        }
        // B tile: Bs[kk][c] = W[kbase+kk][h*128+c]
        {
            int h = k0 >> 7;
            int kbase = k0 & 127;
            int r = tid >> 3;
            int cq = (tid & 7) * 4;
            #pragma unroll
            for (int cb = 0; cb < 128; cb += 32) {
                float4 v = *(const float4*)(W + (size_t)(kbase + r) * (H * D) + h * D + cb + cq);
                *(float4*)(&Bs[r][cb + cq]) = v;
            }
        }
        __syncthreads();
        #pragma unroll
        for (int kk = 0; kk < BK; kk++) {
            float a4[4], b4[4];
            *(float4*)a4 = *(const float4*)(&As[kk][tm * 4]);
            *(float4*)b4 = *(const float4*)(&Bs[kk][tn * 4]);
            #pragma unroll
            for (int i = 0; i < 4; i++)
                #pragma unroll
                for (int j = 0; j < 4; j++) acc[i][j] += a4[i] * b4[j];
        }
        __syncthreads();
    }

    const float inv6 = 1.0f / 6.0f;
    #pragma unroll
    for (int i = 0; i < 4; i++) {
        int m = m0 + tm * 4 + i;
        if (m < M) {
            #pragma unroll
            for (int j = 0; j < 4; j++) {
                int c = tn * 4 + j;
                float v = acc[i][j] * inv6 + bias[c];
                out[(size_t)m * D + c] = v > 0.f ? v : 0.f;
            }
        }
    }
}

// ---------------- host ----------------

extern "C" void kernel_launch(void* const* d_in, const int* in_sizes, int n_in,
                              void* d_out, int out_size, void* d_ws, size_t ws_size,
                              hipStream_t stream) {
    const float* x_in = (const float*)d_in[0];
    const int* ei = (const int*)d_in[1];
    int N = in_sizes[0] / D;
    int E = in_sizes[1] / 2;
    const int* srcp = ei;
    const int* dstp = ei + E;

    float* ws = (float*)d_ws;
    float* bufA = ws;
    float* bufB = bufA + (size_t)N * D;
    float* abuf = bufB + (size_t)N * D;
    float* wa = abuf + (size_t)N * 12;
    float* agg = wa + 128 * 12;
    int* rowptr = (int*)(agg + (size_t)N * (H * D));
    int* deg = rowptr + (N + 1);
    int* col = deg + N;

    // CSR build
    hipMemsetAsync(deg, 0, (size_t)N * sizeof(int), stream);
    hist_kernel<<<(E + 255) / 256, 256, 0, stream>>>(dstp, deg, E);
    scan_kernel<<<1, 1024, 0, stream>>>(deg, rowptr, N);
    scatter_kernel<<<(E + 255) / 256, 256, 0, stream>>>(srcp, dstp, rowptr, col, E);

    const float* xcur = x_in;
    for (int l = 0; l < 4; l++) {
        const float* W  = (const float*)d_in[2 + 4 * l];
        const float* as_ = (const float*)d_in[3 + 4 * l];
        const float* ad_ = (const float*)d_in[4 + 4 * l];
        const float* b  = (const float*)d_in[5 + 4 * l];
        float* xout = (l == 3) ? (float*)d_out : ((l & 1) ? bufB : bufA);

        fold_att_kernel<<<6, 256, 0, stream>>>(W, as_, ad_, wa);
        compute_a_kernel<<<(N + 3) / 4, 256, 0, stream>>>(xcur, wa, abuf, N);
        aggregate_kernel<<<(N + 3) / 4, 256, 0, stream>>>(xcur, abuf, rowptr, deg, col, agg, N);
        gemm_out_kernel<<<(N + BM - 1) / BM, 256, 0, stream>>>(agg, W, b, xout, N);

        xcur = xout;
    }
}

// Round 2
// 434.542 us; speedup vs baseline: 1.3226x; 1.3226x over previous
//
#include <hip/hip_runtime.h>
#include <math.h>

#define H 6
#define D 128

// ---------------- CSR build ----------------

__global__ __launch_bounds__(256) void hist_kernel(const int* __restrict__ dst,
                                                   int* __restrict__ deg, int E) {
    int e = blockIdx.x * blockDim.x + threadIdx.x;
    if (e < E) atomicAdd(&deg[dst[e]], 1);
}

__global__ __launch_bounds__(1024) void scan_kernel(const int* __restrict__ deg,
                                                    int* __restrict__ rowptr, int n) {
    __shared__ int wsum[16];
    __shared__ int carry;
    if (threadIdx.x == 0) carry = 0;
    __syncthreads();
    int lane = threadIdx.x & 63;
    int wv = (int)(threadIdx.x >> 6);
    for (int base = 0; base < n; base += 1024) {
        int i = base + (int)threadIdx.x;
        int v = (i < n) ? deg[i] : 0;
        int s = v;
        #pragma unroll
        for (int off = 1; off < 64; off <<= 1) {
            int t = __shfl_up(s, off, 64);
            if (lane >= off) s += t;
        }
        if (lane == 63) wsum[wv] = s;
        __syncthreads();
        if (threadIdx.x < 16) {
            int t = wsum[threadIdx.x];
            #pragma unroll
            for (int off = 1; off < 16; off <<= 1) {
                int u = __shfl_up(t, off, 64);
                if ((int)threadIdx.x >= off) t += u;
            }
            wsum[threadIdx.x] = t;
        }
        __syncthreads();
        int woff = (wv > 0) ? wsum[wv - 1] : 0;
        if (i < n) rowptr[i] = carry + woff + s - v;  // exclusive prefix
        __syncthreads();
        if (threadIdx.x == 0) carry += wsum[15];
        __syncthreads();
    }
}

__global__ __launch_bounds__(256) void scatter_kernel(const int* __restrict__ src,
                                                      const int* __restrict__ dst,
                                                      int* __restrict__ rowcur,
                                                      int* __restrict__ col, int E) {
    int e = blockIdx.x * blockDim.x + threadIdx.x;
    if (e < E) {
        int p = atomicAdd(&rowcur[dst[e]], 1);
        col[p] = src[e];
    }
}

// ---------------- per-layer kernels ----------------

__global__ __launch_bounds__(256) void fold_att_kernel(const float* __restrict__ W,
                                                       const float* __restrict__ att_src,
                                                       const float* __restrict__ att_dst,
                                                       float* __restrict__ wa) {
    int t = blockIdx.x * blockDim.x + threadIdx.x;
    if (t >= 128 * 12) return;
    int k = t / 12, j = t % 12;
    int h = (j < 6) ? j : (j - 6);
    const float* att = (j < 6) ? att_src : att_dst;
    const float* wrow = W + (size_t)k * (H * D) + h * D;
    const float* arow = att + h * D;
    float s = 0.f;
    #pragma unroll 8
    for (int c = 0; c < D; c++) s += wrow[c] * arow[c];
    wa[k * 12 + j] = s;
}

// a[n][j] = x[n,:] @ wa[:,j]   (one wave per node)
__global__ __launch_bounds__(256) void compute_a_kernel(const float* __restrict__ x,
                                                        const float* __restrict__ wa,
                                                        float* __restrict__ a, int n_nodes) {
    __shared__ float swa[128 * 12];
    for (int i = threadIdx.x; i < 128 * 12; i += 256) swa[i] = wa[i];
    __syncthreads();
    int wid = (int)((blockIdx.x * blockDim.x + threadIdx.x) >> 6);
    int lane = threadIdx.x & 63;
    if (wid >= n_nodes) return;
    float x0 = x[(size_t)wid * D + lane];
    float x1 = x[(size_t)wid * D + 64 + lane];
    #pragma unroll
    for (int j = 0; j < 12; j++) {
        float p = x0 * swa[lane * 12 + j] + x1 * swa[(64 + lane) * 12 + j];
        #pragma unroll
        for (int off = 32; off; off >>= 1) p += __shfl_xor(p, off, 64);
        if (lane == 0) a[(size_t)wid * 12 + j] = p;
    }
}

// One wave per dst node. Fast path (deg+1 <= 64): lane-parallel softmax,
// shuffle-broadcast accumulation (x-load addresses depend only on shuffles,
// so consecutive j iterations pipeline).
__global__ __launch_bounds__(256) void aggregate_kernel(const float* __restrict__ x,
                                                        const float* __restrict__ a,
                                                        const int* __restrict__ rowend,
                                                        const int* __restrict__ deg_,
                                                        const int* __restrict__ col,
                                                        float* __restrict__ agg, int n_nodes) {
    int wid = (int)((blockIdx.x * blockDim.x + threadIdx.x) >> 6);
    int lane = threadIdx.x & 63;
    if (wid >= n_nodes) return;
    const int n = wid;
    const int deg = deg_[n];
    const int start = rowend[n] - deg;
    const int nent = deg + 1;

    float adst[H];
    #pragma unroll
    for (int h = 0; h < H; h++) adst[h] = a[(size_t)n * 12 + 6 + h];

    float* og = agg + (size_t)n * (H * D);

    if (nent <= 64) {
        const bool act = lane < nent;
        int s = n;                           // lane 'deg' = self loop; inactive lanes benign
        if (lane < deg) s = col[start + lane];

        const float* as_ = a + (size_t)s * 12;
        float4 v0 = *(const float4*)as_;     // (s*12*4)%16==0: aligned
        float2 v1 = *(const float2*)(as_ + 4);
        float e0 = v0.x + adst[0], e1 = v0.y + adst[1], e2 = v0.z + adst[2];
        float e3 = v0.w + adst[3], e4 = v1.x + adst[4], e5 = v1.y + adst[5];
        e0 = e0 > 0.f ? e0 : 0.2f * e0;  e1 = e1 > 0.f ? e1 : 0.2f * e1;
        e2 = e2 > 0.f ? e2 : 0.2f * e2;  e3 = e3 > 0.f ? e3 : 0.2f * e3;
        e4 = e4 > 0.f ? e4 : 0.2f * e4;  e5 = e5 > 0.f ? e5 : 0.2f * e5;
        if (!act) { e0 = e1 = e2 = e3 = e4 = e5 = -1e30f; }

        float m0 = e0, m1 = e1, m2 = e2, m3 = e3, m4 = e4, m5 = e5;
        #pragma unroll
        for (int off = 32; off; off >>= 1) {
            m0 = fmaxf(m0, __shfl_xor(m0, off, 64));
            m1 = fmaxf(m1, __shfl_xor(m1, off, 64));
            m2 = fmaxf(m2, __shfl_xor(m2, off, 64));
            m3 = fmaxf(m3, __shfl_xor(m3, off, 64));
            m4 = fmaxf(m4, __shfl_xor(m4, off, 64));
            m5 = fmaxf(m5, __shfl_xor(m5, off, 64));
        }
        float w0 = act ? __expf(e0 - m0) : 0.f;
        float w1 = act ? __expf(e1 - m1) : 0.f;
        float w2 = act ? __expf(e2 - m2) : 0.f;
        float w3 = act ? __expf(e3 - m3) : 0.f;
        float w4 = act ? __expf(e4 - m4) : 0.f;
        float w5 = act ? __expf(e5 - m5) : 0.f;
        float d0 = w0, d1 = w1, d2 = w2, d3 = w3, d4 = w4, d5 = w5;
        #pragma unroll
        for (int off = 32; off; off >>= 1) {
            d0 += __shfl_xor(d0, off, 64);  d1 += __shfl_xor(d1, off, 64);
            d2 += __shfl_xor(d2, off, 64);  d3 += __shfl_xor(d3, off, 64);
            d4 += __shfl_xor(d4, off, 64);  d5 += __shfl_xor(d5, off, 64);
        }
        w0 *= 1.f / (d0 + 1e-16f);  w1 *= 1.f / (d1 + 1e-16f);
        w2 *= 1.f / (d2 + 1e-16f);  w3 *= 1.f / (d3 + 1e-16f);
        w4 *= 1.f / (d4 + 1e-16f);  w5 *= 1.f / (d5 + 1e-16f);

        float a00 = 0, a01 = 0, a02 = 0, a03 = 0, a04 = 0, a05 = 0;
        float a10 = 0, a11 = 0, a12 = 0, a13 = 0, a14 = 0, a15 = 0;
        const float* xb0 = x + lane;
        const float* xb1 = x + 64 + lane;
        for (int j = 0; j < nent; j++) {
            int sj = __shfl(s, j, 64);
            float b0 = __shfl(w0, j, 64), b1 = __shfl(w1, j, 64), b2 = __shfl(w2, j, 64);
            float b3 = __shfl(w3, j, 64), b4 = __shfl(w4, j, 64), b5 = __shfl(w5, j, 64);
            float xv0 = xb0[(size_t)sj * D];
            float xv1 = xb1[(size_t)sj * D];
            a00 += b0 * xv0; a01 += b1 * xv0; a02 += b2 * xv0;
            a03 += b3 * xv0; a04 += b4 * xv0; a05 += b5 * xv0;
            a10 += b0 * xv1; a11 += b1 * xv1; a12 += b2 * xv1;
            a13 += b3 * xv1; a14 += b4 * xv1; a15 += b5 * xv1;
        }
        og[0 * D + lane] = a00;  og[1 * D + lane] = a01;  og[2 * D + lane] = a02;
        og[3 * D + lane] = a03;  og[4 * D + lane] = a04;  og[5 * D + lane] = a05;
        og[0 * D + 64 + lane] = a10;  og[1 * D + 64 + lane] = a11;  og[2 * D + 64 + lane] = a12;
        og[3 * D + 64 + lane] = a13;  og[4 * D + 64 + lane] = a14;  og[5 * D + 64 + lane] = a15;
    } else {
        // ---- slow fallback (deg >= 64): serial two-pass, correct for any degree ----
        float m[H];
        #pragma unroll
        for (int h = 0; h < H; h++) {
            float e = a[(size_t)n * 12 + h] + adst[h];
            m[h] = (e > 0.f) ? e : 0.2f * e;
        }
        for (int j = 0; j < deg; j++) {
            int s = col[start + j];
            #pragma unroll
            for (int h = 0; h < H; h++) {
                float e = a[(size_t)s * 12 + h] + adst[h];
                e = (e > 0.f) ? e : 0.2f * e;
                m[h] = fmaxf(m[h], e);
            }
        }
        float d[H] = {0, 0, 0, 0, 0, 0};
        float acc0[H] = {0, 0, 0, 0, 0, 0};
        float acc1[H] = {0, 0, 0, 0, 0, 0};
        int c0 = lane, c1 = 64 + lane;
        for (int j = 0; j <= deg; j++) {
            int s = (j < deg) ? col[start + j] : n;
            float w[H];
            #pragma unroll
            for (int h = 0; h < H; h++) {
                float e = a[(size_t)s * 12 + h] + adst[h];
                e = (e > 0.f) ? e : 0.2f * e;
                w[h] = __expf(e - m[h]);
                d[h] += w[h];
            }
            float xv0 = x[(size_t)s * D + c0];
            float xv1 = x[(size_t)s * D + c1];
            #pragma unroll
            for (int h = 0; h < H; h++) {
                acc0[h] += w[h] * xv0;
                acc1[h] += w[h] * xv1;
            }
        }
        #pragma unroll
        for (int h = 0; h < H; h++) {
            float inv = 1.0f / (d[h] + 1e-16f);
            og[h * D + c0] = acc0[h] * inv;
            og[h * D + c1] = acc1[h] * inv;
        }
    }
}

// out[m][c] = relu( (1/6) * sum_kk agg[m][kk] * W[kk%128][(kk/128)*128 + c] + bias[c] )
#define BM 32
#define BN 64
#define BKK 64
__global__ __launch_bounds__(256) void gemm_out_kernel(const float* __restrict__ A,
                                                       const float* __restrict__ W,
                                                       const float* __restrict__ bias,
                                                       float* __restrict__ out, int M) {
    __shared__ float As[BM][BKK + 4];   // 32 x 68 (pad keeps 16B row alignment)
    __shared__ float Bs[BKK][BN];       // 64 x 64
    const int m0 = blockIdx.x * BM;
    const int c0 = blockIdx.y * BN;
    const int tid = threadIdx.x;
    const int tn = tid & 15;        // 16 threads x 4 cols = 64
    const int tmq = tid >> 4;       // 16 groups x 2 rows = 32

    float acc[2][4] = {{0.f}};

    for (int k0 = 0; k0 < H * D; k0 += BKK) {
        // stage A tile: 32 rows x 64 k (2 float4 per thread)
        {
            int ra = tid >> 3;
            int cq = (tid & 7) * 8;
            int m = m0 + ra;
            float4 va = make_float4(0, 0, 0, 0), vb = make_float4(0, 0, 0, 0);
            if (m < M) {
                const float* src = A + (size_t)m * (H * D) + k0 + cq;
                va = *(const float4*)src;
                vb = *(const float4*)(src + 4);
            }
            *(float4*)&As[ra][cq] = va;
            *(float4*)&As[ra][cq + 4] = vb;
        }
        // stage B tile: Bs[r][c] = W[(k0&127)+r][(k0>>7)*128 + c0 + c]
        // linear chunk mapping -> perfectly coalesced, conflict-free LDS writes
        {
            int h128 = (k0 >> 7) * 128;
            int kb = k0 & 127;
            #pragma unroll
            for (int i = 0; i < 4; i++) {
                int j = i * 256 + tid;
                int r = j >> 4;
                int cc = (j & 15) * 4;
                float4 v = *(const float4*)(W + (size_t)(kb + r) * (H * D) + h128 + c0 + cc);
                *(float4*)&Bs[r][cc] = v;
            }
        }
        __syncthreads();
        #pragma unroll
        for (int kk = 0; kk < BKK; kk++) {
            float a0 = As[tmq * 2][kk];
            float a1 = As[tmq * 2 + 1][kk];
            float4 b = *(const float4*)&Bs[kk][tn * 4];
            acc[0][0] += a0 * b.x; acc[0][1] += a0 * b.y;
            acc[0][2] += a0 * b.z; acc[0][3] += a0 * b.w;
            acc[1][0] += a1 * b.x; acc[1][1] += a1 * b.y;
            acc[1][2] += a1 * b.z; acc[1][3] += a1 * b.w;
        }
        __syncthreads();
    }

    const float inv6 = 1.0f / 6.0f;
    #pragma unroll
    for (int i = 0; i < 2; i++) {
        int m = m0 + tmq * 2 + i;
        if (m < M) {
            #pragma unroll
            for (int j = 0; j < 4; j++) {
                int c = c0 + tn * 4 + j;
                float v = acc[i][j] * inv6 + bias[c];
                out[(size_t)m * D + c] = v > 0.f ? v : 0.f;
            }
        }
    }
}

// ---------------- host ----------------

extern "C" void kernel_launch(void* const* d_in, const int* in_sizes, int n_in,
                              void* d_out, int out_size, void* d_ws, size_t ws_size,
                              hipStream_t stream) {
    const float* x_in = (const float*)d_in[0];
    const int* ei = (const int*)d_in[1];
    int N = in_sizes[0] / D;
    int E = in_sizes[1] / 2;
    const int* srcp = ei;
    const int* dstp = ei + E;

    float* ws = (float*)d_ws;
    float* bufA = ws;
    float* bufB = bufA + (size_t)N * D;
    float* abuf = bufB + (size_t)N * D;
    float* wa = abuf + (size_t)N * 12;
    float* agg = wa + 128 * 12;
    int* rowptr = (int*)(agg + (size_t)N * (H * D));
    int* deg = rowptr + (N + 1);
    int* col = deg + N;

    // CSR build
    hipMemsetAsync(deg, 0, (size_t)N * sizeof(int), stream);
    hist_kernel<<<(E + 255) / 256, 256, 0, stream>>>(dstp, deg, E);
    scan_kernel<<<1, 1024, 0, stream>>>(deg, rowptr, N);
    scatter_kernel<<<(E + 255) / 256, 256, 0, stream>>>(srcp, dstp, rowptr, col, E);

    const float* xcur = x_in;
    for (int l = 0; l < 4; l++) {
        const float* W   = (const float*)d_in[2 + 4 * l];
        const float* as_ = (const float*)d_in[3 + 4 * l];
        const float* ad_ = (const float*)d_in[4 + 4 * l];
        const float* b   = (const float*)d_in[5 + 4 * l];
        float* xout = (l == 3) ? (float*)d_out : ((l & 1) ? bufB : bufA);

        fold_att_kernel<<<6, 256, 0, stream>>>(W, as_, ad_, wa);
        compute_a_kernel<<<(N + 3) / 4, 256, 0, stream>>>(xcur, wa, abuf, N);
        aggregate_kernel<<<(N + 3) / 4, 256, 0, stream>>>(xcur, abuf, rowptr, deg, col, agg, N);
        gemm_out_kernel<<<dim3((N + BM - 1) / BM, D / BN), 256, 0, stream>>>(agg, W, b, xout, N);

        xcur = xout;
    }
}